// Round 1
// baseline (97.798 us; speedup 1.0000x reference)
//
#include <hip/hip_runtime.h>

#define NB 50
#define BLOCK 256

// out = relu(x@W1+b1) . V[id] + c[id]
// V[id][k] = sum_j W2[k][j]*Wh[id][j]   (folded second layer + head)
// c[id]    = sum_j b2[j]*Wh[id][j] + bh[id]
//
// LDS V layout is XOR-swizzled at float4 granularity:
//   entry (id, k) lives at float index (id<<5) | (((k>>2)^id)&7)<<2 | (k&3)
// so the divergent per-lane row gather spreads across all 8 bank groups
// instead of hammering one 4-bank group (128 B rows are a multiple of the
// 128 B bank period).

__device__ __forceinline__ float dot4relu(float x0, float x1,
                                          float4 wa, float4 wb, float4 bb,
                                          float4 v, float acc)
{
    float h;
    h = fmaf(x0, wa.x, fmaf(x1, wb.x, bb.x)); h = fmaxf(h, 0.f); acc = fmaf(h, v.x, acc);
    h = fmaf(x0, wa.y, fmaf(x1, wb.y, bb.y)); h = fmaxf(h, 0.f); acc = fmaf(h, v.y, acc);
    h = fmaf(x0, wa.z, fmaf(x1, wb.z, bb.z)); h = fmaxf(h, 0.f); acc = fmaf(h, v.z, acc);
    h = fmaf(x0, wa.w, fmaf(x1, wb.w, bb.w)); h = fmaxf(h, 0.f); acc = fmaf(h, v.w, acc);
    return acc;
}

__global__ __launch_bounds__(BLOCK) void lightwin_kernel(
    const float4* __restrict__ xq,    // [B/2] float4 = two (x0,x1) rows each
    const int4*   __restrict__ bq,    // [B/4]
    const float*  __restrict__ W1,    // [2][32]
    const float*  __restrict__ b1,    // [32]
    const float*  __restrict__ W2,    // [32][16]
    const float*  __restrict__ b2,    // [16]
    const float*  __restrict__ Wh,    // [50][16]
    const float*  __restrict__ bh,    // [50]
    float4*       __restrict__ outq,  // [B/4]
    int nq)
{
    __shared__ float sV[NB * 32];
    __shared__ float sc[NB];

    // ---- per-block precompute of folded weights into LDS (swizzled) ----
    for (int t = threadIdx.x; t < NB * 32; t += BLOCK) {
        int id = t >> 5;
        int k  = t & 31;
        float s = 0.f;
        #pragma unroll
        for (int j = 0; j < 16; ++j)
            s = fmaf(W2[(k << 4) + j], Wh[(id << 4) + j], s);
        sV[(id << 5) | (((((unsigned)k >> 2) ^ (unsigned)id) & 7u) << 2) | (k & 3)] = s;
    }
    for (int t = threadIdx.x; t < NB; t += BLOCK) {
        float s = bh[t];
        #pragma unroll
        for (int j = 0; j < 16; ++j)
            s = fmaf(b2[j], Wh[(t << 4) + j], s);
        sc[t] = s;
    }
    __syncthreads();

    int tid = blockIdx.x * BLOCK + threadIdx.x;
    if (tid >= nq) return;

    // ---- load 4 elements ----
    float4 xa = xq[2 * tid];        // elems 4t, 4t+1
    float4 xb = xq[2 * tid + 1];    // elems 4t+2, 4t+3
    int4 ib = bq[tid];
    int id0 = ib.x < NB ? ib.x : NB - 1;
    int id1 = ib.y < NB ? ib.y : NB - 1;
    int id2 = ib.z < NB ? ib.z : NB - 1;
    int id3 = ib.w < NB ? ib.w : NB - 1;

    const float4* sV4 = (const float4*)sV;
    const float4* W14 = (const float4*)W1;
    const float4* b14 = (const float4*)b1;

    float acc0 = sc[id0];
    float acc1 = sc[id1];
    float acc2 = sc[id2];
    float acc3 = sc[id3];

    #pragma unroll
    for (int kb = 0; kb < 8; ++kb) {
        float4 wa = W14[kb];        // W1[0][4kb..4kb+3]  (uniform -> s_load)
        float4 wb = W14[8 + kb];    // W1[1][4kb..4kb+3]
        float4 bb = b14[kb];
        float4 v0 = sV4[(id0 << 3) | (((unsigned)(kb ^ id0)) & 7u)];
        float4 v1 = sV4[(id1 << 3) | (((unsigned)(kb ^ id1)) & 7u)];
        float4 v2 = sV4[(id2 << 3) | (((unsigned)(kb ^ id2)) & 7u)];
        float4 v3 = sV4[(id3 << 3) | (((unsigned)(kb ^ id3)) & 7u)];
        acc0 = dot4relu(xa.x, xa.y, wa, wb, bb, v0, acc0);
        acc1 = dot4relu(xa.z, xa.w, wa, wb, bb, v1, acc1);
        acc2 = dot4relu(xb.x, xb.y, wa, wb, bb, v2, acc2);
        acc3 = dot4relu(xb.z, xb.w, wa, wb, bb, v3, acc3);
    }

    float4 o; o.x = acc0; o.y = acc1; o.z = acc2; o.w = acc3;
    outq[tid] = o;
}

extern "C" void kernel_launch(void* const* d_in, const int* in_sizes, int n_in,
                              void* d_out, int out_size, void* d_ws, size_t ws_size,
                              hipStream_t stream) {
    const float* x       = (const float*)d_in[0];
    const int*   buckets = (const int*)d_in[1];
    const float* W1      = (const float*)d_in[2];
    const float* b1      = (const float*)d_in[3];
    const float* W2      = (const float*)d_in[4];
    const float* b2      = (const float*)d_in[5];
    const float* Wh      = (const float*)d_in[6];
    const float* bh      = (const float*)d_in[7];
    float* out = (float*)d_out;

    int B  = in_sizes[1];   // bucket count == batch
    int nq = B / 4;         // B = 2,000,000 -> divisible by 4
    int grid = (nq + BLOCK - 1) / BLOCK;

    lightwin_kernel<<<grid, BLOCK, 0, stream>>>(
        (const float4*)x, (const int4*)buckets, W1, b1, W2, b2, Wh, bh,
        (float4*)out, nq);
}

// Round 2
// 89.864 us; speedup vs baseline: 1.0883x; 1.0883x over previous
//
#include <hip/hip_runtime.h>

#define NB 50
#define BLOCK 256

// out = relu(x@W1+b1) . V[id] + c[id]
//   V[id][k] = sum_j W2[k][j]*Wh[id][j]   (second layer folded into head)
//   c[id]    = sum_j b2[j]*Wh[id][j] + bh[id]
//
// Phase 1 (precompute kernel): V (bank-swizzled) + c -> d_ws (1650 floats).
// Phase 2 (main kernel): coalesced ws->LDS staging, then 4 elems/thread.
//
// LDS swizzle at float4 granularity: entry (id, k) lives at float index
//   (id<<5) | ((((k>>2) ^ h(id)) & 7) << 2) | (k&3),  h(id) = (id + (id>>3)) & 7
// h() breaks mod-8 residue classes (ids 1,9,17,...,49 -> 7 distinct groups),
// spreading the ~36 distinct rows/wave across all 8 bank groups.

__global__ __launch_bounds__(BLOCK) void precompute_kernel(
    const float* __restrict__ W2,   // [32][16]
    const float* __restrict__ b2,   // [16]
    const float* __restrict__ Wh,   // [50][16]
    const float* __restrict__ bh,   // [50]
    float*       __restrict__ ws)   // [1664]: V swizzled [0..1599], c [1600..1649]
{
    int t = blockIdx.x * BLOCK + threadIdx.x;
    if (t < NB * 32) {
        int id = t >> 5;
        int k  = t & 31;
        float s = 0.f;
        #pragma unroll
        for (int j = 0; j < 16; ++j)
            s = fmaf(W2[(k << 4) + j], Wh[(id << 4) + j], s);
        int h = (id + (id >> 3)) & 7;
        ws[(id << 5) | ((((k >> 2) ^ h) & 7) << 2) | (k & 3)] = s;
    } else if (t < NB * 32 + NB) {
        int id = t - NB * 32;
        float s = bh[id];
        #pragma unroll
        for (int j = 0; j < 16; ++j)
            s = fmaf(b2[j], Wh[(id << 4) + j], s);
        ws[NB * 32 + id] = s;
    }
}

__device__ __forceinline__ float dot4relu(float x0, float x1,
                                          float4 wa, float4 wb, float4 bb,
                                          float4 v, float acc)
{
    float h;
    h = fmaf(x0, wa.x, fmaf(x1, wb.x, bb.x)); h = fmaxf(h, 0.f); acc = fmaf(h, v.x, acc);
    h = fmaf(x0, wa.y, fmaf(x1, wb.y, bb.y)); h = fmaxf(h, 0.f); acc = fmaf(h, v.y, acc);
    h = fmaf(x0, wa.z, fmaf(x1, wb.z, bb.z)); h = fmaxf(h, 0.f); acc = fmaf(h, v.z, acc);
    h = fmaf(x0, wa.w, fmaf(x1, wb.w, bb.w)); h = fmaxf(h, 0.f); acc = fmaf(h, v.w, acc);
    return acc;
}

__global__ __launch_bounds__(BLOCK) void lightwin_kernel(
    const float4* __restrict__ xq,    // [B/2]
    const int4*   __restrict__ bq,    // [B/4]
    const float*  __restrict__ W1,    // [2][32]
    const float*  __restrict__ b1,    // [32]
    const float4* __restrict__ wsq,   // [416] (1664 floats; 1650 valid)
    float4*       __restrict__ outq,  // [B/4]
    int nq)
{
    __shared__ float sVc[416 * 4];    // V swizzled [0..1599] + c [1600..1649]

    int tid = blockIdx.x * BLOCK + threadIdx.x;
    bool active = tid < nq;

    // Issue global loads first so their latency overlaps the LDS staging.
    float4 xa = {}, xb = {};
    int4 ib = {};
    if (active) {
        xa = xq[2 * tid];
        xb = xq[2 * tid + 1];
        ib = bq[tid];
    }

    // Coalesced ws -> LDS staging (already swizzled), 2 float4/thread.
    float4* sq = (float4*)sVc;
    #pragma unroll
    for (int t = threadIdx.x; t < 416; t += BLOCK)
        sq[t] = wsq[t];
    __syncthreads();

    if (!active) return;

    int id0 = ib.x < NB ? ib.x : NB - 1;
    int id1 = ib.y < NB ? ib.y : NB - 1;
    int id2 = ib.z < NB ? ib.z : NB - 1;
    int id3 = ib.w < NB ? ib.w : NB - 1;
    int h0 = (id0 + (id0 >> 3)) & 7;
    int h1 = (id1 + (id1 >> 3)) & 7;
    int h2 = (id2 + (id2 >> 3)) & 7;
    int h3 = (id3 + (id3 >> 3)) & 7;

    const float4* sV4 = (const float4*)sVc;
    const float*  sc  = sVc + NB * 32;
    const float4* W14 = (const float4*)W1;
    const float4* b14 = (const float4*)b1;

    float acc0 = sc[id0];
    float acc1 = sc[id1];
    float acc2 = sc[id2];
    float acc3 = sc[id3];

    #pragma unroll
    for (int kb = 0; kb < 8; ++kb) {
        float4 wa = W14[kb];        // W1[0][4kb..]  (wave-uniform -> scalar loads)
        float4 wb = W14[8 + kb];    // W1[1][4kb..]
        float4 bb = b14[kb];
        float4 v0 = sV4[(id0 << 3) | ((kb ^ h0) & 7)];
        float4 v1 = sV4[(id1 << 3) | ((kb ^ h1) & 7)];
        float4 v2 = sV4[(id2 << 3) | ((kb ^ h2) & 7)];
        float4 v3 = sV4[(id3 << 3) | ((kb ^ h3) & 7)];
        acc0 = dot4relu(xa.x, xa.y, wa, wb, bb, v0, acc0);
        acc1 = dot4relu(xa.z, xa.w, wa, wb, bb, v1, acc1);
        acc2 = dot4relu(xb.x, xb.y, wa, wb, bb, v2, acc2);
        acc3 = dot4relu(xb.z, xb.w, wa, wb, bb, v3, acc3);
    }

    float4 o; o.x = acc0; o.y = acc1; o.z = acc2; o.w = acc3;
    outq[tid] = o;
}

extern "C" void kernel_launch(void* const* d_in, const int* in_sizes, int n_in,
                              void* d_out, int out_size, void* d_ws, size_t ws_size,
                              hipStream_t stream) {
    const float* x       = (const float*)d_in[0];
    const int*   buckets = (const int*)d_in[1];
    const float* W1      = (const float*)d_in[2];
    const float* b1      = (const float*)d_in[3];
    const float* W2      = (const float*)d_in[4];
    const float* b2      = (const float*)d_in[5];
    const float* Wh      = (const float*)d_in[6];
    const float* bh      = (const float*)d_in[7];
    float* out = (float*)d_out;
    float* ws  = (float*)d_ws;

    int B  = in_sizes[1];   // 2,000,000
    int nq = B / 4;

    precompute_kernel<<<(NB * 32 + NB + BLOCK - 1) / BLOCK, BLOCK, 0, stream>>>(
        W2, b2, Wh, bh, ws);

    int grid = (nq + BLOCK - 1) / BLOCK;
    lightwin_kernel<<<grid, BLOCK, 0, stream>>>(
        (const float4*)x, (const int4*)buckets, W1, b1,
        (const float4*)ws, (float4*)out, nq);
}

// Round 4
// 89.826 us; speedup vs baseline: 1.0887x; 1.0004x over previous
//
#include <hip/hip_runtime.h>

#define NB 50
#define BLOCK 256

// out = relu(x@W1+b1) . V[id] + c[id]
//   V[id][k] = sum_j W2[k][j]*Wh[id][j]   (second layer folded into head)
//   c[id]    = sum_j b2[j]*Wh[id][j] + bh[id]
//
// V is stored fp16, TRANSPOSED-PAIR layout: half2 slot = k2*64 + id
// (k2 = k/2, stride padded to 64). For a ds_read_b32 at fixed k2, lane bank
// = id % 32 -> at most 2 distinct addresses per bank (id vs id+32), and
// 2-way LDS aliasing is free on gfx950. k2 offsets fold into the DS
// 16-bit immediate (k2*256 bytes), so address math is ~1 VALU per element.
//
// All packed-half math uses clang-native _Float16 ext-vectors (ROCm 7.2's
// __hmax2/__hfma2 overload set is broken for __half2 here); * and + lower
// to v_pk_fma_f16 under HIP's default fp-contract, ReLU via
// __builtin_elementwise_max.
//
// ws layout (uint32 units):
//   [   0,1024): VhT half2 bits, slot k2*64+id (ids 50..63 zero)
//   [1024,1088): c[id] float bits (50 valid)
//   [1088,1104): w0h2[k2] = (W1[0][2k2], W1[0][2k2+1]) as half2
//   [1104,1120): w1h2[k2]
//   [1120,1136): bh2[k2]  = (b1[2k2], b1[2k2+1])
// Main kernel stages [0,1088) into LDS; weight half2s are read uniformly
// from global ws (scalar loads).

typedef _Float16 hvec2 __attribute__((ext_vector_type(2)));

union h2bits { unsigned u; hvec2 h; };

__device__ __forceinline__ hvec2 u2h2(unsigned u) {
    h2bits c; c.u = u; return c.h;
}

__device__ __forceinline__ float dot2acc(hvec2 a, hvec2 b, float c) {
#if __has_builtin(__builtin_amdgcn_fdot2)
    return __builtin_amdgcn_fdot2(a, b, c, false);
#else
    return fmaf((float)a.x, (float)b.x, fmaf((float)a.y, (float)b.y, c));
#endif
}

__global__ __launch_bounds__(BLOCK) void precompute_kernel(
    const float* __restrict__ W1,   // [2][32]
    const float* __restrict__ b1,   // [32]
    const float* __restrict__ W2,   // [32][16]
    const float* __restrict__ b2,   // [16]
    const float* __restrict__ Wh,   // [50][16]
    const float* __restrict__ bh,   // [50]
    unsigned*    __restrict__ ws)
{
    int t = blockIdx.x * BLOCK + threadIdx.x;
    if (t < 1024) {
        int k2 = t >> 6;
        int id = t & 63;
        unsigned bits = 0u;
        if (id < NB) {
            float f0 = 0.f, f1 = 0.f;
            int k0 = 2 * k2, k1 = 2 * k2 + 1;
            #pragma unroll
            for (int j = 0; j < 16; ++j) {
                f0 = fmaf(W2[(k0 << 4) + j], Wh[(id << 4) + j], f0);
                f1 = fmaf(W2[(k1 << 4) + j], Wh[(id << 4) + j], f1);
            }
            h2bits c;
            c.h.x = (_Float16)f0;
            c.h.y = (_Float16)f1;
            bits = c.u;
        }
        ws[t] = bits;
    } else if (t < 1088) {
        int id = t - 1024;
        unsigned bits = 0u;
        if (id < NB) {
            float s = bh[id];
            #pragma unroll
            for (int j = 0; j < 16; ++j)
                s = fmaf(b2[j], Wh[(id << 4) + j], s);
            bits = __float_as_uint(s);
        }
        ws[t] = bits;
    } else if (t < 1136) {
        int i = t - 1088;
        int plane = i >> 4;         // 0:w0 1:w1 2:b
        int k2 = i & 15;
        float f0, f1;
        if (plane == 0)      { f0 = W1[2 * k2];      f1 = W1[2 * k2 + 1]; }
        else if (plane == 1) { f0 = W1[32 + 2 * k2]; f1 = W1[32 + 2 * k2 + 1]; }
        else                 { f0 = b1[2 * k2];      f1 = b1[2 * k2 + 1]; }
        h2bits c;
        c.h.x = (_Float16)f0;
        c.h.y = (_Float16)f1;
        ws[t] = c.u;
    }
}

__global__ __launch_bounds__(BLOCK) void lightwin_kernel(
    const float4*   __restrict__ xq,    // [B/2]
    const int4*     __restrict__ bq,    // [B/4]
    const unsigned* __restrict__ wsu,
    float4*         __restrict__ outq,  // [B/4]
    int nq)
{
    __shared__ unsigned sU[1088];       // VhT [0,1024) + c bits [1024,1088)

    int tid = blockIdx.x * BLOCK + threadIdx.x;
    bool active = tid < nq;

    // Issue per-element global loads first to overlap LDS staging.
    float4 xa = {}, xb = {};
    int4 ib = {};
    if (active) {
        xa = xq[2 * tid];
        xb = xq[2 * tid + 1];
        ib = bq[tid];
    }

    // Coalesced staging: 1088 uints = 272 float4.
    {
        float4* sq = (float4*)sU;
        const float4* wq = (const float4*)wsu;
        for (int t = threadIdx.x; t < 272; t += BLOCK)
            sq[t] = wq[t];
    }
    __syncthreads();
    if (!active) return;

    int id0 = ib.x < NB ? ib.x : NB - 1;
    int id1 = ib.y < NB ? ib.y : NB - 1;
    int id2 = ib.z < NB ? ib.z : NB - 1;
    int id3 = ib.w < NB ? ib.w : NB - 1;

    float acc0 = __uint_as_float(sU[1024 + id0]);
    float acc1 = __uint_as_float(sU[1024 + id1]);
    float acc2 = __uint_as_float(sU[1024 + id2]);
    float acc3 = __uint_as_float(sU[1024 + id3]);

    // Broadcast x into packed halves.
    #define SPLAT2(f) (hvec2){(_Float16)(f), (_Float16)(f)}
    hvec2 x0e0 = SPLAT2(xa.x), x1e0 = SPLAT2(xa.y);
    hvec2 x0e1 = SPLAT2(xa.z), x1e1 = SPLAT2(xa.w);
    hvec2 x0e2 = SPLAT2(xb.x), x1e2 = SPLAT2(xb.y);
    hvec2 x0e3 = SPLAT2(xb.z), x1e3 = SPLAT2(xb.w);
    const hvec2 z2 = (hvec2)0;

    const unsigned* wp0 = wsu + 1088;   // uniform -> s_load
    const unsigned* wp1 = wsu + 1104;
    const unsigned* wpb = wsu + 1120;

    #pragma unroll
    for (int k2 = 0; k2 < 16; ++k2) {
        hvec2 w0 = u2h2(wp0[k2]);
        hvec2 w1 = u2h2(wp1[k2]);
        hvec2 bb = u2h2(wpb[k2]);
        // h2 = relu(x0*w0 + x1*w1 + b) in packed fp16 (contracts to v_pk_fma);
        // dot2 accumulate in f32.
        hvec2 h0 = __builtin_elementwise_max(x0e0 * w0 + x1e0 * w1 + bb, z2);
        hvec2 h1 = __builtin_elementwise_max(x0e1 * w0 + x1e1 * w1 + bb, z2);
        hvec2 h2 = __builtin_elementwise_max(x0e2 * w0 + x1e2 * w1 + bb, z2);
        hvec2 h3 = __builtin_elementwise_max(x0e3 * w0 + x1e3 * w1 + bb, z2);
        acc0 = dot2acc(h0, u2h2(sU[(k2 << 6) + id0]), acc0);
        acc1 = dot2acc(h1, u2h2(sU[(k2 << 6) + id1]), acc1);
        acc2 = dot2acc(h2, u2h2(sU[(k2 << 6) + id2]), acc2);
        acc3 = dot2acc(h3, u2h2(sU[(k2 << 6) + id3]), acc3);
    }

    float4 o; o.x = acc0; o.y = acc1; o.z = acc2; o.w = acc3;
    outq[tid] = o;
}

extern "C" void kernel_launch(void* const* d_in, const int* in_sizes, int n_in,
                              void* d_out, int out_size, void* d_ws, size_t ws_size,
                              hipStream_t stream) {
    const float* x       = (const float*)d_in[0];
    const int*   buckets = (const int*)d_in[1];
    const float* W1      = (const float*)d_in[2];
    const float* b1      = (const float*)d_in[3];
    const float* W2      = (const float*)d_in[4];
    const float* b2      = (const float*)d_in[5];
    const float* Wh      = (const float*)d_in[6];
    const float* bh      = (const float*)d_in[7];
    float* out = (float*)d_out;
    unsigned* ws = (unsigned*)d_ws;

    int B  = in_sizes[1];   // 2,000,000
    int nq = B / 4;

    precompute_kernel<<<(1136 + BLOCK - 1) / BLOCK, BLOCK, 0, stream>>>(
        W1, b1, W2, b2, Wh, bh, ws);

    int grid = (nq + BLOCK - 1) / BLOCK;
    lightwin_kernel<<<grid, BLOCK, 0, stream>>>(
        (const float4*)x, (const int4*)buckets, ws, (float4*)out, nq);
}